// Round 9
// baseline (215.659 us; speedup 1.0000x reference)
//
#include <hip/hip_runtime.h>
#include <hip/hip_fp16.h>
#include <math.h>

#define D 128
#define D4 32        // uints per fp8 row
#define AP 136       // padded LDS row stride (halves) for MFMA staging
#define AP8 144      // padded LDS row stride (bytes) for fp8 C staging (16B aligned)
#define NBUCK 256    // coarse dst-buckets
#define EPB 8192     // edges per pass1 block
#define BCAP2 8192   // per-bucket capacity (mean 6250, sd ~79 -> 24 sigma slack)

typedef _Float16 f16x8 __attribute__((ext_vector_type(8)));
typedef float f32x4 __attribute__((ext_vector_type(4)));
typedef float f32x2 __attribute__((ext_vector_type(2)));

// ---------------- weight prep (both) + bcnt zero: one dispatch ----------------
// blocks 0..63 -> W1, 64..127 -> W2. Block 0 also zeroes bcnt (runs before pass1
// via same-stream ordering).

__global__ void prep_all_kernel(const float* __restrict__ W1, _Float16* __restrict__ Wt1,
                                const float* __restrict__ W2, _Float16* __restrict__ Wt2,
                                int* __restrict__ bcnt) {
    int t = threadIdx.x;
    if (blockIdx.x == 0) bcnt[t] = 0;
    int half = blockIdx.x & 63;
    const float* W = (blockIdx.x < 64) ? W1 : W2;
    _Float16* Wt   = (blockIdx.x < 64) ? Wt1 : Wt2;
    int i = half * 256 + t;      // i = k*128 + c
    int k = i >> 7, c = i & 127;
    Wt[c * 128 + k] = (_Float16)W[i];
}

// ---------------- CSR build: 2-level LDS counting sort, all stores wave-dense --------

__global__ __launch_bounds__(256) void bucket_pass1(const int* __restrict__ src,
                                                    const int* __restrict__ dst,
                                                    int* __restrict__ bcnt,
                                                    unsigned* __restrict__ buckets,
                                                    int E, unsigned magicM) {
    __shared__ unsigned raw[EPB];    // 32KB
    __shared__ unsigned stage[EPB];  // 32KB
    __shared__ int lcnt[NBUCK], loff[NBUCK], gbase[NBUCK], sc[NBUCK];

    int t = threadIdx.x;
    int base = blockIdx.x * EPB;
    int nblk = min(EPB, E - base);
    lcnt[t] = 0;
    __syncthreads();

    for (int i = t; i < nblk; i += 256) {
        unsigned s = (unsigned)src[base + i];
        unsigned d = (unsigned)dst[base + i];
        unsigned pk = (s << 16) | d;
        raw[i] = pk;
        int b = (int)(((unsigned long long)d * magicM) >> 24);
        atomicAdd(&lcnt[b], 1);
    }
    __syncthreads();

    int v = lcnt[t];
    sc[t] = v;
    __syncthreads();
    for (int off = 1; off < 256; off <<= 1) {
        int x = (t >= off) ? sc[t - off] : 0;
        __syncthreads();
        sc[t] += x;
        __syncthreads();
    }
    loff[t] = sc[t] - v;                       // exclusive
    gbase[t] = atomicAdd(&bcnt[t], v);         // global reservation per (block,bucket)
    lcnt[t] = 0;                               // reuse as cursor
    __syncthreads();

    for (int i = t; i < nblk; i += 256) {      // place into LDS, bucket-ordered
        unsigned pk = raw[i];
        int b = (int)(((unsigned long long)(pk & 0xffffu) * magicM) >> 24);
        int p = atomicAdd(&lcnt[b], 1);
        stage[loff[b] + p] = pk;
    }
    __syncthreads();

    for (int i = t; i < nblk; i += 256) {      // dense copy-out
        unsigned pk = stage[i];
        int b = (int)(((unsigned long long)(pk & 0xffffu) * magicM) >> 24);
        int pos = gbase[b] + (i - loff[b]);
        if (pos < BCAP2) buckets[(size_t)b * BCAP2 + pos] = pk;
    }
}

// Pass 2: one block per bucket. Redundant per-block scan of bcnt (removes the
// separate scan dispatch), LDS-count exact nodes, local scan -> row_ptr/dis,
// LDS-place col entries, dense coalesced u16 col-segment write.
__global__ __launch_bounds__(256) void csr_pass2(const unsigned* __restrict__ buckets,
                                                 const int* __restrict__ bcnt,
                                                 int* __restrict__ row_ptr,
                                                 float* __restrict__ dis,
                                                 unsigned short* __restrict__ col,
                                                 int N, int npb, int E) {
    __shared__ int cnt[256], sc[256], excl[256];
    __shared__ unsigned short estage[16384];   // 32KB

    int b = blockIdx.x;
    int t = threadIdx.x;

    // per-block scan of bcnt -> this bucket's global base
    int bv = min(bcnt[t], BCAP2);
    sc[t] = bv;
    __syncthreads();
    for (int off = 1; off < 256; off <<= 1) {
        int x = (t >= off) ? sc[t - off] : 0;
        __syncthreads();
        sc[t] += x;
        __syncthreads();
    }
    int base = sc[b] - min(bcnt[b], BCAP2);    // exclusive prefix at b (uniform read)
    if (b == 0 && t == 0) row_ptr[N] = E;
    __syncthreads();

    int lo = b * npb;
    int nn = min(npb, N - lo);
    int n = min(bcnt[b], BCAP2);
    const unsigned* bk = buckets + (size_t)b * BCAP2;

    cnt[t] = 0;
    __syncthreads();
    for (int i = t; i < n; i += 256) {
        int dl = (int)(bk[i] & 0xffffu) - lo;
        atomicAdd(&cnt[dl], 1);
    }
    __syncthreads();
    int v = cnt[t];
    sc[t] = v;
    __syncthreads();
    for (int off = 1; off < 256; off <<= 1) {
        int x = (t >= off) ? sc[t - off] : 0;
        __syncthreads();
        sc[t] += x;
        __syncthreads();
    }
    excl[t] = sc[t] - v;
    if (t < nn) {
        row_ptr[lo + t] = base + excl[t];
        dis[lo + t] = rsqrtf((float)v + 1.0f);
    }
    cnt[t] = 0;   // reuse as cursor
    __syncthreads();
    for (int i = t; i < n; i += 256) {
        unsigned pk = bk[i];
        int dl = (int)(pk & 0xffffu) - lo;
        int p = atomicAdd(&cnt[dl], 1);
        estage[excl[dl] + p] = (unsigned short)(pk >> 16);
    }
    __syncthreads();
    for (int i = t; i < n; i += 256) col[base + i] = estage[i];   // dense
}

// ---------------- MFMA GEMM variants: C_fp8[N x 128] = dis[row]*(A @ W) ----------------

#define GEMM_CORE                                                            \
    const uint4* Wt16 = (const uint4*)Wt;                                    \
    for (int i = t; i < 128 * 16; i += 256) {                                \
        int r = i >> 4, ch = i & 15;                                         \
        *(uint4*)&Ws[r * AP + ch * 8] = Wt16[i];                             \
    }                                                                        \
    __syncthreads();                                                         \
    int wave = t >> 6;                                                       \
    int lane = t & 63;                                                       \
    int m16 = lane & 15;                                                     \
    int quad = lane >> 4;                                                    \
    f32x4 acc[8];                                                            \
    for (int n = 0; n < 8; n++) acc[n] = (f32x4){0.f, 0.f, 0.f, 0.f};        \
    _Pragma("unroll")                                                        \
    for (int kc = 0; kc < 4; kc++) {                                         \
        f16x8 a = *(const f16x8*)&As[(wave * 16 + m16) * AP + kc * 32 + quad * 8]; \
        _Pragma("unroll")                                                    \
        for (int n = 0; n < 8; n++) {                                        \
            f16x8 bfrag = *(const f16x8*)&Ws[(n * 16 + m16) * AP + kc * 32 + quad * 8]; \
            acc[n] = __builtin_amdgcn_mfma_f32_16x16x32_f16(a, bfrag, acc[n], 0, 0, 0); \
        }                                                                    \
    }                                                                        \
    __syncthreads();                                                         \
    unsigned char* Cs8 = (unsigned char*)As;                                 \
    float dv[4];                                                             \
    _Pragma("unroll")                                                        \
    for (int r = 0; r < 4; r++) {                                            \
        int grow = row0 + wave * 16 + quad * 4 + r;                          \
        dv[r] = (grow < N) ? dis[grow] : 0.f;                                \
    }                                                                        \
    _Pragma("unroll")                                                        \
    for (int n = 0; n < 8; n++)                                              \
        _Pragma("unroll")                                                    \
        for (int r = 0; r < 4; r++) {                                        \
            float val = acc[n][r] * dv[r];                                   \
            int wq = __builtin_amdgcn_cvt_pk_fp8_f32(val, val, 0, false);    \
            Cs8[(wave * 16 + quad * 4 + r) * AP8 + n * 16 + m16] = (unsigned char)(wq & 0xff); \
        }                                                                    \
    __syncthreads();                                                         \
    uint4* C16 = (uint4*)C8;                                                 \
    for (int i = lane; i < 128; i += 64) {                                   \
        int r = i >> 3, ch = i & 7;                                          \
        int grow = row0 + wave * 16 + r;                                     \
        if (grow < N)                                                        \
            C16[(size_t)grow * 8 + ch] = *(const uint4*)&Cs8[(wave * 16 + r) * AP8 + ch * 16]; \
    }

__global__ __launch_bounds__(256) void gemm_f32a_fp8c(const float* __restrict__ A,
                                                      const _Float16* __restrict__ Wt,
                                                      const float* __restrict__ dis,
                                                      unsigned int* __restrict__ C8, int N) {
    __shared__ _Float16 As[64 * AP];
    __shared__ _Float16 Ws[128 * AP];
    int t = threadIdx.x;
    int row0 = blockIdx.x * 64;
    const float4* A4 = (const float4*)A;
    for (int i = t; i < 64 * 16; i += 256) {
        int r = i >> 4, ch = i & 15;
        uint4 v = make_uint4(0, 0, 0, 0);
        if (row0 + r < N) {
            float4 a0 = A4[(size_t)(row0 + r) * 32 + ch * 2];
            float4 a1 = A4[(size_t)(row0 + r) * 32 + ch * 2 + 1];
            __half2 h0 = __floats2half2_rn(a0.x, a0.y);
            __half2 h1 = __floats2half2_rn(a0.z, a0.w);
            __half2 h2 = __floats2half2_rn(a1.x, a1.y);
            __half2 h3 = __floats2half2_rn(a1.z, a1.w);
            v.x = *(unsigned*)&h0; v.y = *(unsigned*)&h1;
            v.z = *(unsigned*)&h2; v.w = *(unsigned*)&h3;
        }
        *(uint4*)&As[r * AP + ch * 8] = v;
    }
    GEMM_CORE
}

__global__ __launch_bounds__(256) void gemm_f16a_fp8c(const _Float16* __restrict__ A,
                                                      const _Float16* __restrict__ Wt,
                                                      const float* __restrict__ dis,
                                                      unsigned int* __restrict__ C8, int N) {
    __shared__ _Float16 As[64 * AP];
    __shared__ _Float16 Ws[128 * AP];
    int t = threadIdx.x;
    int row0 = blockIdx.x * 64;
    const uint4* A16 = (const uint4*)A;
    for (int i = t; i < 64 * 16; i += 256) {
        int r = i >> 4, ch = i & 15;
        uint4 v = make_uint4(0, 0, 0, 0);
        if (row0 + r < N) v = A16[(size_t)(row0 + r) * 16 + ch];
        *(uint4*)&As[r * AP + ch * 8] = v;
    }
    GEMM_CORE
}

// ---------------- Aggregation (pull, fp8 table = 1 line/edge, u16 col) ----------------
// Full-32 unrolled gather: 32 outstanding 128B gathers per 32-lane node group
// (table is 6.4MB > 4MB/XCD L2 -> ~40% MALL-latency gathers; MLP is the lever).

__device__ __forceinline__ void acc8(float4& a, unsigned int u) {
    f32x2 lo = __builtin_amdgcn_cvt_pk_f32_fp8((int)u, false);
    f32x2 hi = __builtin_amdgcn_cvt_pk_f32_fp8((int)u, true);
    a.x += lo[0]; a.y += lo[1]; a.z += hi[0]; a.w += hi[1];
}

#define AGG8_BODY                                                               \
    float4 acc = make_float4(0.f, 0.f, 0.f, 0.f);                               \
    acc8(acc, t8[(size_t)node * D4 + lane]); /* self term (pre-scaled) */       \
    int e0 = row_ptr[node], e1 = row_ptr[node + 1];                             \
    int deg = e1 - e0;                                                          \
    for (int base = 0; base < deg; base += 32) {                                \
        int cnt = min(32, deg - base);                                          \
        int myc = (base + lane < deg) ? (int)col[e0 + base + lane] : 0;         \
        if (cnt == 32) {                                                        \
            unsigned u[32];                                                     \
            _Pragma("unroll")                                                   \
            for (int j = 0; j < 32; j++) {                                      \
                int s = __shfl(myc, j, 32);                                     \
                u[j] = t8[(size_t)s * D4 + lane];                               \
            }                                                                   \
            _Pragma("unroll")                                                   \
            for (int j = 0; j < 32; j++) acc8(acc, u[j]);                       \
        } else {                                                                \
            int j = 0;                                                          \
            for (; j + 8 <= cnt; j += 8) {                                      \
                int s0 = __shfl(myc, j + 0, 32); int s1 = __shfl(myc, j + 1, 32); \
                int s2 = __shfl(myc, j + 2, 32); int s3 = __shfl(myc, j + 3, 32); \
                int s4 = __shfl(myc, j + 4, 32); int s5 = __shfl(myc, j + 5, 32); \
                int s6 = __shfl(myc, j + 6, 32); int s7 = __shfl(myc, j + 7, 32); \
                unsigned int u0 = t8[(size_t)s0 * D4 + lane];                   \
                unsigned int u1 = t8[(size_t)s1 * D4 + lane];                   \
                unsigned int u2 = t8[(size_t)s2 * D4 + lane];                   \
                unsigned int u3 = t8[(size_t)s3 * D4 + lane];                   \
                unsigned int u4 = t8[(size_t)s4 * D4 + lane];                   \
                unsigned int u5 = t8[(size_t)s5 * D4 + lane];                   \
                unsigned int u6 = t8[(size_t)s6 * D4 + lane];                   \
                unsigned int u7 = t8[(size_t)s7 * D4 + lane];                   \
                acc8(acc, u0); acc8(acc, u1); acc8(acc, u2); acc8(acc, u3);     \
                acc8(acc, u4); acc8(acc, u5); acc8(acc, u6); acc8(acc, u7);     \
            }                                                                   \
            for (; j < cnt; j++) {                                              \
                int s = __shfl(myc, j, 32);                                     \
                acc8(acc, t8[(size_t)s * D4 + lane]);                           \
            }                                                                   \
        }                                                                       \
    }                                                                           \
    float di = dis[node];                                                       \
    float4 bb = ((const float4*)bias)[lane];                                    \
    float4 o;                                                                   \
    o.x = fmaxf(fmaf(di, acc.x, bb.x), 0.f);                                    \
    o.y = fmaxf(fmaf(di, acc.y, bb.y), 0.f);                                    \
    o.z = fmaxf(fmaf(di, acc.z, bb.z), 0.f);                                    \
    o.w = fmaxf(fmaf(di, acc.w, bb.w), 0.f);

// layer-1: writes x1 fp16 (feeds gemm2 A-operand)
__global__ void agg_fp8_kernel(const unsigned int* __restrict__ t8, const float* __restrict__ bias,
                               const int* __restrict__ row_ptr, const unsigned short* __restrict__ col,
                               const float* __restrict__ dis, _Float16* __restrict__ xout, int N) {
    int t = threadIdx.x;
    int node = blockIdx.x * 8 + (t >> 5);
    int lane = t & 31;
    if (node >= N) return;
    AGG8_BODY
    __half2 q0 = __floats2half2_rn(o.x, o.y);
    __half2 q1 = __floats2half2_rn(o.z, o.w);
    uint2 u;
    u.x = *(unsigned int*)&q0;
    u.y = *(unsigned int*)&q1;
    ((uint2*)xout)[(size_t)node * D4 + lane] = u;
}

// layer-2: fused sigmoid head, one score per node
__global__ void agg_head_fp8_kernel(const unsigned int* __restrict__ t8, const float* __restrict__ bias,
                                    const int* __restrict__ row_ptr, const unsigned short* __restrict__ col,
                                    const float* __restrict__ dis,
                                    const float* __restrict__ head_w, const float* __restrict__ head_b,
                                    float* __restrict__ out, int N) {
    int t = threadIdx.x;
    int node = blockIdx.x * 8 + (t >> 5);
    int lane = t & 31;
    if (node >= N) return;
    AGG8_BODY
    float4 wv = ((const float4*)head_w)[lane];
    float s = o.x * wv.x + o.y * wv.y + o.z * wv.z + o.w * wv.w;
    for (int m = 1; m < 32; m <<= 1) s += __shfl_xor(s, m, 64);
    if (lane == 0) {
        float v = s + head_b[0];
        out[node] = 1.0f / (1.0f + expf(-v));
    }
}

// ---------------- launch ----------------

extern "C" void kernel_launch(void* const* d_in, const int* in_sizes, int n_in,
                              void* d_out, int out_size, void* d_ws, size_t ws_size,
                              hipStream_t stream) {
    const int*   edge   = (const int*)d_in[0];
    const float* emb    = (const float*)d_in[1];
    const float* W1     = (const float*)d_in[2];
    const float* b1     = (const float*)d_in[3];
    const float* W2     = (const float*)d_in[4];
    const float* b2     = (const float*)d_in[5];
    const float* head_w = (const float*)d_in[6];
    const float* head_b = (const float*)d_in[7];
    float* out = (float*)d_out;

    int E = in_sizes[0] / 2;
    int N = in_sizes[1] / D;
    const int* srcp = edge;
    const int* dstp = edge + E;

    char* w = (char*)d_ws;
    auto alloc = [&](size_t bytes) -> char* {
        char* p = w;
        w += (bytes + 15) & ~(size_t)15;
        return p;
    };
    unsigned int*   t8      = (unsigned int*)alloc((size_t)N * D);          // 6.4 MB fp8 table
    _Float16*       x1h     = (_Float16*)alloc((size_t)N * D * 2);          // 12.8 MB x1 fp16
    unsigned*       buckets = (unsigned*)alloc((size_t)NBUCK * BCAP2 * 4);  // 8 MB
    _Float16*       Wt1     = (_Float16*)alloc((size_t)D * D * 2);
    _Float16*       Wt2     = (_Float16*)alloc((size_t)D * D * 2);
    unsigned short* col     = (unsigned short*)alloc((size_t)E * 2);        // 3.2 MB
    int*            bcnt    = (int*)alloc(NBUCK * 4);
    int*            row_ptr = (int*)alloc((size_t)(N + 1) * 4);
    float*          dis     = (float*)alloc((size_t)N * 4);

    int npb = (N + NBUCK - 1) / NBUCK;                     // nodes per bucket (196)
    unsigned magicM = (16777216u + (unsigned)npb - 1) / (unsigned)npb;
    int gP1 = (E + EPB - 1) / EPB;                         // 196
    int gG = (N + 63) / 64;
    int gA = (N + 7) / 8;

    prep_all_kernel<<<128, 256, 0, stream>>>(W1, Wt1, W2, Wt2, bcnt);
    bucket_pass1<<<gP1, 256, 0, stream>>>(srcp, dstp, bcnt, buckets, E, magicM);
    csr_pass2<<<NBUCK, 256, 0, stream>>>(buckets, bcnt, row_ptr, dis, col, N, npb, E);

    gemm_f32a_fp8c<<<gG, 256, 0, stream>>>(emb, Wt1, dis, t8, N);                 // hs1 fp8
    agg_fp8_kernel<<<gA, 256, 0, stream>>>(t8, b1, row_ptr, col, dis, x1h, N);    // x1 fp16
    gemm_f16a_fp8c<<<gG, 256, 0, stream>>>(x1h, Wt2, dis, t8, N);                 // hs2 fp8
    agg_head_fp8_kernel<<<gA, 256, 0, stream>>>(t8, b2, row_ptr, col, dis,
                                                head_w, head_b, out, N);          // scores
}

// Round 10
// 209.552 us; speedup vs baseline: 1.0291x; 1.0291x over previous
//
#include <hip/hip_runtime.h>
#include <hip/hip_fp16.h>
#include <math.h>

#define D 128
#define D4 32        // uints per fp8 row
#define AP 136       // padded LDS row stride (halves) for MFMA staging
#define AP8 144      // padded LDS row stride (bytes) for fp8 C staging (16B aligned)
#define NBUCK 256    // coarse dst-buckets
#define EPB 8192     // edges per pass1 block
#define BCAP2 8192   // per-bucket capacity (mean 6250, sd ~79 -> 24 sigma slack)

typedef _Float16 f16x8 __attribute__((ext_vector_type(8)));
typedef float f32x4 __attribute__((ext_vector_type(4)));
typedef float f32x2 __attribute__((ext_vector_type(2)));

// ---------------- weight prep (both) + bcnt zero: one dispatch ----------------

__global__ void prep_all_kernel(const float* __restrict__ W1, _Float16* __restrict__ Wt1,
                                const float* __restrict__ W2, _Float16* __restrict__ Wt2,
                                int* __restrict__ bcnt) {
    int t = threadIdx.x;
    if (blockIdx.x == 0) bcnt[t] = 0;
    int half = blockIdx.x & 63;
    const float* W = (blockIdx.x < 64) ? W1 : W2;
    _Float16* Wt   = (blockIdx.x < 64) ? Wt1 : Wt2;
    int i = half * 256 + t;      // i = k*128 + c
    int k = i >> 7, c = i & 127;
    Wt[c * 128 + k] = (_Float16)W[i];
}

// ---------------- CSR build: 2-level LDS counting sort, all stores wave-dense --------
// Pass 1, slim-LDS variant: no raw[] buffer; the edge chunk is re-read from global
// (2nd/3rd reads hit the same XCD's L2). 34KB LDS -> 4 blocks/CU for the
// latency-bound LDS-atomic loops (was 2 at 66KB).

__global__ __launch_bounds__(256) void bucket_pass1(const int* __restrict__ src,
                                                    const int* __restrict__ dst,
                                                    int* __restrict__ bcnt,
                                                    unsigned* __restrict__ buckets,
                                                    int E, unsigned magicM) {
    __shared__ unsigned stage[EPB];  // 32KB
    __shared__ int lcnt[NBUCK], loff[NBUCK], gbase[NBUCK];

    int t = threadIdx.x;
    int base = blockIdx.x * EPB;
    int nblk = min(EPB, E - base);
    lcnt[t] = 0;
    __syncthreads();

    for (int i = t; i < nblk; i += 256) {
        unsigned d = (unsigned)dst[base + i];
        int b = (int)(((unsigned long long)d * magicM) >> 24);
        atomicAdd(&lcnt[b], 1);
    }
    __syncthreads();

    int v = lcnt[t];
    loff[t] = v;   // will become inclusive scan, then exclusive
    __syncthreads();
    for (int off = 1; off < 256; off <<= 1) {
        int x = (t >= off) ? loff[t - off] : 0;
        __syncthreads();
        loff[t] += x;
        __syncthreads();
    }
    int incl = loff[t];
    __syncthreads();
    loff[t] = incl - v;                        // exclusive
    gbase[t] = atomicAdd(&bcnt[t], v);         // global reservation per (block,bucket)
    lcnt[t] = 0;                               // reuse as cursor
    __syncthreads();

    for (int i = t; i < nblk; i += 256) {      // place into LDS, bucket-ordered
        unsigned s = (unsigned)src[base + i];
        unsigned d = (unsigned)dst[base + i];
        unsigned pk = (s << 16) | d;
        int b = (int)(((unsigned long long)d * magicM) >> 24);
        int p = atomicAdd(&lcnt[b], 1);
        stage[loff[b] + p] = pk;
    }
    __syncthreads();

    for (int i = t; i < nblk; i += 256) {      // dense copy-out
        unsigned pk = stage[i];
        int b = (int)(((unsigned long long)(pk & 0xffffu) * magicM) >> 24);
        int pos = gbase[b] + (i - loff[b]);
        if (pos < BCAP2) buckets[(size_t)b * BCAP2 + pos] = pk;
    }
}

// Pass 2: one block per bucket. Per-block scan of bcnt (no separate dispatch),
// LDS-count exact nodes, local scan -> row_ptr/dis, LDS-place col entries,
// dense coalesced u16 col-segment write.
__global__ __launch_bounds__(256) void csr_pass2(const unsigned* __restrict__ buckets,
                                                 const int* __restrict__ bcnt,
                                                 int* __restrict__ row_ptr,
                                                 float* __restrict__ dis,
                                                 unsigned short* __restrict__ col,
                                                 int N, int npb, int E) {
    __shared__ int cnt[256], sc[256], excl[256];
    __shared__ unsigned short estage[16384];   // 32KB

    int b = blockIdx.x;
    int t = threadIdx.x;

    int bv = min(bcnt[t], BCAP2);
    sc[t] = bv;
    __syncthreads();
    for (int off = 1; off < 256; off <<= 1) {
        int x = (t >= off) ? sc[t - off] : 0;
        __syncthreads();
        sc[t] += x;
        __syncthreads();
    }
    int base = sc[b] - min(bcnt[b], BCAP2);    // exclusive prefix at b (uniform read)
    if (b == 0 && t == 0) row_ptr[N] = E;
    __syncthreads();

    int lo = b * npb;
    int nn = min(npb, N - lo);
    int n = min(bcnt[b], BCAP2);
    const unsigned* bk = buckets + (size_t)b * BCAP2;

    cnt[t] = 0;
    __syncthreads();
    for (int i = t; i < n; i += 256) {
        int dl = (int)(bk[i] & 0xffffu) - lo;
        atomicAdd(&cnt[dl], 1);
    }
    __syncthreads();
    int v = cnt[t];
    sc[t] = v;
    __syncthreads();
    for (int off = 1; off < 256; off <<= 1) {
        int x = (t >= off) ? sc[t - off] : 0;
        __syncthreads();
        sc[t] += x;
        __syncthreads();
    }
    excl[t] = sc[t] - v;
    if (t < nn) {
        row_ptr[lo + t] = base + excl[t];
        dis[lo + t] = rsqrtf((float)v + 1.0f);
    }
    cnt[t] = 0;   // reuse as cursor
    __syncthreads();
    for (int i = t; i < n; i += 256) {
        unsigned pk = bk[i];
        int dl = (int)(pk & 0xffffu) - lo;
        int p = atomicAdd(&cnt[dl], 1);
        estage[excl[dl] + p] = (unsigned short)(pk >> 16);
    }
    __syncthreads();
    for (int i = t; i < n; i += 256) col[base + i] = estage[i];   // dense
}

// ---------------- MFMA GEMM variants: C_fp8[N x 128] = dis[row]*(A @ W) ----------------

#define GEMM_CORE                                                            \
    const uint4* Wt16 = (const uint4*)Wt;                                    \
    for (int i = t; i < 128 * 16; i += 256) {                                \
        int r = i >> 4, ch = i & 15;                                         \
        *(uint4*)&Ws[r * AP + ch * 8] = Wt16[i];                             \
    }                                                                        \
    __syncthreads();                                                         \
    int wave = t >> 6;                                                       \
    int lane = t & 63;                                                       \
    int m16 = lane & 15;                                                     \
    int quad = lane >> 4;                                                    \
    f32x4 acc[8];                                                            \
    for (int n = 0; n < 8; n++) acc[n] = (f32x4){0.f, 0.f, 0.f, 0.f};        \
    _Pragma("unroll")                                                        \
    for (int kc = 0; kc < 4; kc++) {                                         \
        f16x8 a = *(const f16x8*)&As[(wave * 16 + m16) * AP + kc * 32 + quad * 8]; \
        _Pragma("unroll")                                                    \
        for (int n = 0; n < 8; n++) {                                        \
            f16x8 bfrag = *(const f16x8*)&Ws[(n * 16 + m16) * AP + kc * 32 + quad * 8]; \
            acc[n] = __builtin_amdgcn_mfma_f32_16x16x32_f16(a, bfrag, acc[n], 0, 0, 0); \
        }                                                                    \
    }                                                                        \
    __syncthreads();                                                         \
    unsigned char* Cs8 = (unsigned char*)As;                                 \
    float dv[4];                                                             \
    _Pragma("unroll")                                                        \
    for (int r = 0; r < 4; r++) {                                            \
        int grow = row0 + wave * 16 + quad * 4 + r;                          \
        dv[r] = (grow < N) ? dis[grow] : 0.f;                                \
    }                                                                        \
    _Pragma("unroll")                                                        \
    for (int n = 0; n < 8; n++)                                              \
        _Pragma("unroll")                                                    \
        for (int r = 0; r < 4; r++) {                                        \
            float val = acc[n][r] * dv[r];                                   \
            int wq = __builtin_amdgcn_cvt_pk_fp8_f32(val, val, 0, false);    \
            Cs8[(wave * 16 + quad * 4 + r) * AP8 + n * 16 + m16] = (unsigned char)(wq & 0xff); \
        }                                                                    \
    __syncthreads();                                                         \
    uint4* C16 = (uint4*)C8;                                                 \
    for (int i = lane; i < 128; i += 64) {                                   \
        int r = i >> 3, ch = i & 7;                                          \
        int grow = row0 + wave * 16 + r;                                     \
        if (grow < N)                                                        \
            C16[(size_t)grow * 8 + ch] = *(const uint4*)&Cs8[(wave * 16 + r) * AP8 + ch * 16]; \
    }

__global__ __launch_bounds__(256) void gemm_f32a_fp8c(const float* __restrict__ A,
                                                      const _Float16* __restrict__ Wt,
                                                      const float* __restrict__ dis,
                                                      unsigned int* __restrict__ C8, int N) {
    __shared__ _Float16 As[64 * AP];
    __shared__ _Float16 Ws[128 * AP];
    int t = threadIdx.x;
    int row0 = blockIdx.x * 64;
    const float4* A4 = (const float4*)A;
    for (int i = t; i < 64 * 16; i += 256) {
        int r = i >> 4, ch = i & 15;
        uint4 v = make_uint4(0, 0, 0, 0);
        if (row0 + r < N) {
            float4 a0 = A4[(size_t)(row0 + r) * 32 + ch * 2];
            float4 a1 = A4[(size_t)(row0 + r) * 32 + ch * 2 + 1];
            __half2 h0 = __floats2half2_rn(a0.x, a0.y);
            __half2 h1 = __floats2half2_rn(a0.z, a0.w);
            __half2 h2 = __floats2half2_rn(a1.x, a1.y);
            __half2 h3 = __floats2half2_rn(a1.z, a1.w);
            v.x = *(unsigned*)&h0; v.y = *(unsigned*)&h1;
            v.z = *(unsigned*)&h2; v.w = *(unsigned*)&h3;
        }
        *(uint4*)&As[r * AP + ch * 8] = v;
    }
    GEMM_CORE
}

__global__ __launch_bounds__(256) void gemm_f16a_fp8c(const _Float16* __restrict__ A,
                                                      const _Float16* __restrict__ Wt,
                                                      const float* __restrict__ dis,
                                                      unsigned int* __restrict__ C8, int N) {
    __shared__ _Float16 As[64 * AP];
    __shared__ _Float16 Ws[128 * AP];
    int t = threadIdx.x;
    int row0 = blockIdx.x * 64;
    const uint4* A16 = (const uint4*)A;
    for (int i = t; i < 64 * 16; i += 256) {
        int r = i >> 4, ch = i & 15;
        uint4 v = make_uint4(0, 0, 0, 0);
        if (row0 + r < N) v = A16[(size_t)(row0 + r) * 16 + ch];
        *(uint4*)&As[r * AP + ch * 8] = v;
    }
    GEMM_CORE
}

// ---------------- Aggregation (pull, fp8 table = 1 line/edge, u16 col) ----------------
// 8-deep unrolled gather (R8-proven best: throughput is line-fetch-rate bound,
// ~20 outstanding lines/CU; deeper unroll only burns VGPRs).

__device__ __forceinline__ void acc8(float4& a, unsigned int u) {
    f32x2 lo = __builtin_amdgcn_cvt_pk_f32_fp8((int)u, false);
    f32x2 hi = __builtin_amdgcn_cvt_pk_f32_fp8((int)u, true);
    a.x += lo[0]; a.y += lo[1]; a.z += hi[0]; a.w += hi[1];
}

#define AGG8_BODY                                                               \
    float4 acc = make_float4(0.f, 0.f, 0.f, 0.f);                               \
    acc8(acc, t8[(size_t)node * D4 + lane]); /* self term (pre-scaled) */       \
    int e0 = row_ptr[node], e1 = row_ptr[node + 1];                             \
    int deg = e1 - e0;                                                          \
    for (int base = 0; base < deg; base += 32) {                                \
        int cnt = min(32, deg - base);                                          \
        int myc = (base + lane < deg) ? (int)col[e0 + base + lane] : 0;         \
        int j = 0;                                                              \
        for (; j + 8 <= cnt; j += 8) {                                          \
            int s0 = __shfl(myc, j + 0, 32); int s1 = __shfl(myc, j + 1, 32);   \
            int s2 = __shfl(myc, j + 2, 32); int s3 = __shfl(myc, j + 3, 32);   \
            int s4 = __shfl(myc, j + 4, 32); int s5 = __shfl(myc, j + 5, 32);   \
            int s6 = __shfl(myc, j + 6, 32); int s7 = __shfl(myc, j + 7, 32);   \
            unsigned int u0 = t8[(size_t)s0 * D4 + lane];                       \
            unsigned int u1 = t8[(size_t)s1 * D4 + lane];                       \
            unsigned int u2 = t8[(size_t)s2 * D4 + lane];                       \
            unsigned int u3 = t8[(size_t)s3 * D4 + lane];                       \
            unsigned int u4 = t8[(size_t)s4 * D4 + lane];                       \
            unsigned int u5 = t8[(size_t)s5 * D4 + lane];                       \
            unsigned int u6 = t8[(size_t)s6 * D4 + lane];                       \
            unsigned int u7 = t8[(size_t)s7 * D4 + lane];                       \
            acc8(acc, u0); acc8(acc, u1); acc8(acc, u2); acc8(acc, u3);         \
            acc8(acc, u4); acc8(acc, u5); acc8(acc, u6); acc8(acc, u7);         \
        }                                                                       \
        for (; j < cnt; j++) {                                                  \
            int s = __shfl(myc, j, 32);                                         \
            acc8(acc, t8[(size_t)s * D4 + lane]);                               \
        }                                                                       \
    }                                                                           \
    float di = dis[node];                                                       \
    float4 bb = ((const float4*)bias)[lane];                                    \
    float4 o;                                                                   \
    o.x = fmaxf(fmaf(di, acc.x, bb.x), 0.f);                                    \
    o.y = fmaxf(fmaf(di, acc.y, bb.y), 0.f);                                    \
    o.z = fmaxf(fmaf(di, acc.z, bb.z), 0.f);                                    \
    o.w = fmaxf(fmaf(di, acc.w, bb.w), 0.f);

// layer-1: writes x1 fp16 (feeds gemm2 A-operand)
__global__ void agg_fp8_kernel(const unsigned int* __restrict__ t8, const float* __restrict__ bias,
                               const int* __restrict__ row_ptr, const unsigned short* __restrict__ col,
                               const float* __restrict__ dis, _Float16* __restrict__ xout, int N) {
    int t = threadIdx.x;
    int node = blockIdx.x * 8 + (t >> 5);
    int lane = t & 31;
    if (node >= N) return;
    AGG8_BODY
    __half2 q0 = __floats2half2_rn(o.x, o.y);
    __half2 q1 = __floats2half2_rn(o.z, o.w);
    uint2 u;
    u.x = *(unsigned int*)&q0;
    u.y = *(unsigned int*)&q1;
    ((uint2*)xout)[(size_t)node * D4 + lane] = u;
}

// layer-2: fused sigmoid head, one score per node
__global__ void agg_head_fp8_kernel(const unsigned int* __restrict__ t8, const float* __restrict__ bias,
                                    const int* __restrict__ row_ptr, const unsigned short* __restrict__ col,
                                    const float* __restrict__ dis,
                                    const float* __restrict__ head_w, const float* __restrict__ head_b,
                                    float* __restrict__ out, int N) {
    int t = threadIdx.x;
    int node = blockIdx.x * 8 + (t >> 5);
    int lane = t & 31;
    if (node >= N) return;
    AGG8_BODY
    float4 wv = ((const float4*)head_w)[lane];
    float s = o.x * wv.x + o.y * wv.y + o.z * wv.z + o.w * wv.w;
    for (int m = 1; m < 32; m <<= 1) s += __shfl_xor(s, m, 64);
    if (lane == 0) {
        float v = s + head_b[0];
        out[node] = 1.0f / (1.0f + expf(-v));
    }
}

// ---------------- launch ----------------

extern "C" void kernel_launch(void* const* d_in, const int* in_sizes, int n_in,
                              void* d_out, int out_size, void* d_ws, size_t ws_size,
                              hipStream_t stream) {
    const int*   edge   = (const int*)d_in[0];
    const float* emb    = (const float*)d_in[1];
    const float* W1     = (const float*)d_in[2];
    const float* b1     = (const float*)d_in[3];
    const float* W2     = (const float*)d_in[4];
    const float* b2     = (const float*)d_in[5];
    const float* head_w = (const float*)d_in[6];
    const float* head_b = (const float*)d_in[7];
    float* out = (float*)d_out;

    int E = in_sizes[0] / 2;
    int N = in_sizes[1] / D;
    const int* srcp = edge;
    const int* dstp = edge + E;

    char* w = (char*)d_ws;
    auto alloc = [&](size_t bytes) -> char* {
        char* p = w;
        w += (bytes + 15) & ~(size_t)15;
        return p;
    };
    unsigned int*   t8      = (unsigned int*)alloc((size_t)N * D);          // 6.4 MB fp8 table
    _Float16*       x1h     = (_Float16*)alloc((size_t)N * D * 2);          // 12.8 MB x1 fp16
    unsigned*       buckets = (unsigned*)alloc((size_t)NBUCK * BCAP2 * 4);  // 8 MB
    _Float16*       Wt1     = (_Float16*)alloc((size_t)D * D * 2);
    _Float16*       Wt2     = (_Float16*)alloc((size_t)D * D * 2);
    unsigned short* col     = (unsigned short*)alloc((size_t)E * 2);        // 3.2 MB
    int*            bcnt    = (int*)alloc(NBUCK * 4);
    int*            row_ptr = (int*)alloc((size_t)(N + 1) * 4);
    float*          dis     = (float*)alloc((size_t)N * 4);

    int npb = (N + NBUCK - 1) / NBUCK;                     // nodes per bucket (196)
    unsigned magicM = (16777216u + (unsigned)npb - 1) / (unsigned)npb;
    int gP1 = (E + EPB - 1) / EPB;                         // 196
    int gG = (N + 63) / 64;
    int gA = (N + 7) / 8;

    prep_all_kernel<<<128, 256, 0, stream>>>(W1, Wt1, W2, Wt2, bcnt);
    bucket_pass1<<<gP1, 256, 0, stream>>>(srcp, dstp, bcnt, buckets, E, magicM);
    csr_pass2<<<NBUCK, 256, 0, stream>>>(buckets, bcnt, row_ptr, dis, col, N, npb, E);

    gemm_f32a_fp8c<<<gG, 256, 0, stream>>>(emb, Wt1, dis, t8, N);                 // hs1 fp8
    agg_fp8_kernel<<<gA, 256, 0, stream>>>(t8, b1, row_ptr, col, dis, x1h, N);    // x1 fp16
    gemm_f16a_fp8c<<<gG, 256, 0, stream>>>(x1h, Wt2, dis, t8, N);                 // hs2 fp8
    agg_head_fp8_kernel<<<gA, 256, 0, stream>>>(t8, b2, row_ptr, col, dis,
                                                head_w, head_b, out, N);          // scores
}